// Round 9
// baseline (258.221 us; speedup 1.0000x reference)
//
#include <hip/hip_runtime.h>
#include <hip/hip_bf16.h>

#define Bb 2
#define Ss 2048
#define Dd 1024
#define Hh 16
#define Tt ((size_t)Bb*Ss*Dd)   // 4,194,304
#define WNn ((size_t)Dd*Dd)     // 1,048,576

typedef short bf16x8 __attribute__((ext_vector_type(8)));
typedef short bf16x4 __attribute__((ext_vector_type(4)));
typedef float floatx4 __attribute__((ext_vector_type(4)));
typedef unsigned short u16;

__device__ inline void gld16(void* lds, const void* g) {
  __builtin_amdgcn_global_load_lds(
      (const __attribute__((address_space(1))) unsigned int*)g,
      (__attribute__((address_space(3))) unsigned int*)lds, 16, 0, 0);
}

__device__ inline float bf2f(u16 u) {
  unsigned int x = ((unsigned int)u) << 16;
  float f; __builtin_memcpy(&f, &x, 4); return f;
}
__device__ inline u16 f2bf(float f) {
  unsigned int x; __builtin_memcpy(&x, &f, 4);
  x = (x + 0x7fff + ((x >> 16) & 1)) >> 16;   // RNE
  return (u16)x;
}
__device__ inline float u2f(unsigned int x) {
  float f; __builtin_memcpy(&f, &x, 4); return f;
}
// HW packed f32->bf16 (RNE), no builtin on gfx950 -> inline asm.
__device__ inline unsigned int cvtpk(float lo, float hi) {
  unsigned int r;
  asm("v_cvt_pk_bf16_f32 %0, %1, %2" : "=v"(r) : "v"(lo), "v"(hi));
  return r;
}

// ---------------- dtype sniffer (FALLBACK ONLY; host normally resolves dtype
// from in_sizes).
__global__ void sniff(const unsigned int* __restrict__ x, unsigned int* __restrict__ flag,
                      int nwords) {
  __shared__ int cnt;
  if (threadIdx.x == 0) cnt = 0;
  __syncthreads();
  int local = 0;
  for (int i = threadIdx.x; i < nwords; i += blockDim.x) {
    unsigned int wd = x[i];
    if (((wd >> 7)  & 0xFFu) == 0xFFu) local++;
    if (((wd >> 23) & 0xFFu) == 0xFFu) local++;
  }
  atomicAdd(&cnt, local);
  __syncthreads();
  if (threadIdx.x == 0) *flag = (cnt >= 64) ? 1u : 0u;
}

// ---------------- normalize ALL input tensors to bf16 in one launch, and
// (last 32 blocks) precompute the RoPE cos/sin table tab[s][f], f<16.
__global__ __launch_bounds__(256) void convert_all(
    const void* __restrict__ x,  const void* __restrict__ wq,
    const void* __restrict__ wk, const void* __restrict__ wv,
    const void* __restrict__ wo, u16* __restrict__ dst,
    int smode, const unsigned int* __restrict__ flag,
    float2* __restrict__ tab) {
  const int gb = blockIdx.x;
  if (gb >= 4096) {                       // RoPE table: 32 blocks x 256 x 4
    int e = (gb - 4096)*1024 + threadIdx.x*4;
#pragma unroll
    for (int j = 0; j < 4; j++, e++) {
      int s = e >> 4, f = e & 15;
      float freq = exp2f((-10.0f/15.0f) * (float)f);
      float th = (float)s * freq;
      float sn, c;
      sincosf(th, &sn, &c);
      tab[e] = make_float2(c, sn);
    }
    return;
  }
  const void* src; size_t base; int lb;
  if (gb < 2048)      { src = x;  base = 0;            lb = gb;        }
  else if (gb < 2560) { src = wq; base = Tt;           lb = gb - 2048; }
  else if (gb < 3072) { src = wk; base = Tt + WNn;     lb = gb - 2560; }
  else if (gb < 3584) { src = wv; base = Tt + 2*WNn;   lb = gb - 3072; }
  else                { src = wo; base = Tt + 3*WNn;   lb = gb - 3584; }
  const size_t off = (size_t)lb*2048 + threadIdx.x*8;
  const bool f32 = (smode >= 0) ? (smode == 1) : (*flag != 0u);
  bf16x8 v;
  if (f32) {
    const float* s = (const float*)src + off;
#pragma unroll
    for (int j = 0; j < 8; j++) v[j] = (short)f2bf(s[j]);
  } else {
    v = *(const bf16x8*)((const u16*)src + off);
  }
  *(bf16x8*)(dst + base + off) = v;
}

// ---------------- QKV GEMM: C = A(MxK) * W^T, W stored (N,K) row-major.
// m97 structure: 128x128 tile, BK=32, global_load_lds width=16.
// z 0/1 (Q,K): fused RMSNorm+RoPE(table) epilogue, STAGED THROUGH LDS so the
//   global writeback is 8 coalesced bf16x8 stores/lane (was 64 scattered 2B
//   stores -> ~8x L2 sector amplification + 64 store insts).
// z 2 (V): transpose-in-LDS epilogue -> Vt[b][h][dl][s] written as coalesced
//   128B runs along s (was 16x 8B stores at 4KB stride).
// Per-wave sE region; same-wave DS ordering -> no barrier needed.
__global__ __launch_bounds__(256) void gemm_bt(
    const u16* __restrict__ A,
    const u16* __restrict__ W0, const u16* __restrict__ W1, const u16* __restrict__ W2,
    void* __restrict__ C0, void* __restrict__ C1, void* __restrict__ C2,
    int M, int N, int K, const float2* __restrict__ tab)
{
  const u16* W; void* C;
  if (blockIdx.z == 0)      { W = W0; C = C0; }
  else if (blockIdx.z == 1) { W = W1; C = C1; }
  else                      { W = W2; C = C2; }

  __shared__ __align__(16) u16 sA[128*32];
  __shared__ __align__(16) u16 sB[128*32];
  __shared__ __align__(16) u16 sE[4][64*72];    // per-wave 64x64 stage, stride 72

  const int tid  = threadIdx.x;
  const int lane = tid & 63;
  const int w    = tid >> 6;
  const int wm = w >> 1, wn = w & 1;
  const int col = lane & 15, quad = lane >> 4;
  const int bm = blockIdx.y, bn = blockIdx.x;

  floatx4 acc[4][4] = {};

  const int c0 = tid, c1 = tid + 256;
  const size_t aOff0 = (size_t)(bm*128 + (c0 >> 2))*K + (c0 & 3)*8;
  const size_t aOff1 = (size_t)(bm*128 + (c1 >> 2))*K + (c1 & 3)*8;
  const size_t bOff0 = (size_t)(bn*128 + (c0 >> 2))*K + (c0 & 3)*8;
  const size_t bOff1 = (size_t)(bn*128 + (c1 >> 2))*K + (c1 & 3)*8;

  for (int kk = 0; kk < K; kk += 32) {
    gld16(&sA[c0*8], A + aOff0 + kk);
    gld16(&sA[c1*8], A + aOff1 + kk);
    gld16(&sB[c0*8], W + bOff0 + kk);
    gld16(&sB[c1*8], W + bOff1 + kk);
    __syncthreads();
    bf16x8 af[4], bfr[4];
#pragma unroll
    for (int i = 0; i < 4; i++)
      af[i] = *(const bf16x8*)&sA[(wm*64 + i*16 + col)*32 + quad*8];
#pragma unroll
    for (int j = 0; j < 4; j++)
      bfr[j] = *(const bf16x8*)&sB[(wn*64 + j*16 + col)*32 + quad*8];
#pragma unroll
    for (int i = 0; i < 4; i++)
#pragma unroll
      for (int j = 0; j < 4; j++)
        acc[i][j] = __builtin_amdgcn_mfma_f32_16x16x32_bf16(af[i], bfr[j], acc[i][j], 0, 0, 0);
    __syncthreads();
  }

  u16* sEw = &sE[w][0];
  const int rrow = lane >> 3, rch = lane & 7;   // readback: row group, 16B chunk

  if (blockIdx.z == 2) {
    // ---- V: stage transposed [d_local][s_local] (bf16x4 packed over r)
#pragma unroll
    for (int i = 0; i < 4; i++)
#pragma unroll
      for (int j = 0; j < 4; j++) {
        bf16x4 pk;
#pragma unroll
        for (int r = 0; r < 4; r++) pk[r] = (short)f2bf(acc[i][j][r]);
        *(bf16x4*)&sEw[(j*16 + col)*72 + i*16 + quad*4] = pk;
      }
    const int g0 = bm*128 + wm*64;
    const int bb = g0 >> 11, s0 = g0 & (Ss - 1);
    const int hh = (bn*128 + wn*64) >> 6;
    u16* Ct = (u16*)C;
#pragma unroll
    for (int t = 0; t < 8; t++) {
      const int dl = rrow + t*8;
      bf16x8 v = *(const bf16x8*)&sEw[dl*72 + rch*8];
      *(bf16x8*)&Ct[((size_t)(bb*Hh + hh)*64 + dl)*Ss + s0 + rch*8] = v;
    }
  } else {
    // ---- Q/K: RMSNorm (head = wave's 64 cols) + RoPE from table; Q also
    // pre-scaled by 1/sqrt(DH)=0.125 (pow2, exact in bf16). Stage [s][d].
    const float qs = (blockIdx.z == 0) ? 0.125f : 1.0f;
#pragma unroll
    for (int i = 0; i < 4; i++)
#pragma unroll
      for (int r = 0; r < 4; r++) {
        float ss = 0.0f;
#pragma unroll
        for (int j = 0; j < 4; j++) ss += acc[i][j][r]*acc[i][j][r];
        ss += __shfl_xor(ss, 1, 64);
        ss += __shfl_xor(ss, 2, 64);
        ss += __shfl_xor(ss, 4, 64);
        ss += __shfl_xor(ss, 8, 64);
        float rn = rsqrtf(ss*(1.0f/64.0f) + 1e-6f) * qs;
        int grow = bm*128 + wm*64 + i*16 + quad*4 + r;
        float2 cs = tab[(grow & (Ss - 1))*16 + col];
        float x0 = acc[i][0][r]*rn, x1 = acc[i][1][r]*rn;
        float x2 = acc[i][2][r]*rn, x3 = acc[i][3][r]*rn;
        const int lr = (i*16 + quad*4 + r)*72;
        sEw[lr + col]      = f2bf(x0*cs.x + x2*cs.y);
        sEw[lr + 16 + col] = f2bf(x1);
        sEw[lr + 32 + col] = f2bf(x2*cs.x - x0*cs.y);
        sEw[lr + 48 + col] = f2bf(x3);
      }
    u16* Co = (u16*)C;
    const size_t gb = (size_t)(bm*128 + wm*64);
    const int cb = bn*128 + wn*64 + rch*8;
#pragma unroll
    for (int t = 0; t < 8; t++) {
      const int lr = rrow + t*8;
      bf16x8 v = *(const bf16x8*)&sEw[lr*72 + rch*8];
      *(bf16x8*)&Co[(gb + lr)*N + cb] = v;
    }
  }
}

// ---------------- O-projection GEMM: 128x64 tile -> grid (16,32) = 512
// blocks = 2 blocks/CU (the 128x128 version was 256 blocks = 1/CU: every
// barrier+gld16 drain fully exposed; 2/CU restores the m114 implicit
// overlap). 4 waves as 2M x 2N, acc[4][2], B staged with one gld16 round.
__global__ __launch_bounds__(256) void gemm_o(
    const u16* __restrict__ A, const u16* __restrict__ W, void* __restrict__ C,
    int M, int N, int K, const unsigned int* __restrict__ flag, int outMode)
{
  __shared__ __align__(16) u16 sA[128*32];
  __shared__ __align__(16) u16 sB[64*32];

  const int tid  = threadIdx.x;
  const int lane = tid & 63;
  const int w    = tid >> 6;
  const int wm = w >> 1, wn = w & 1;
  const int col = lane & 15, quad = lane >> 4;
  const int bm = blockIdx.y, bn = blockIdx.x;

  floatx4 acc[4][2] = {};

  const int c0 = tid, c1 = tid + 256;
  const size_t aOff0 = (size_t)(bm*128 + (c0 >> 2))*K + (c0 & 3)*8;
  const size_t aOff1 = (size_t)(bm*128 + (c1 >> 2))*K + (c1 & 3)*8;
  const size_t bOff0 = (size_t)(bn*64  + (c0 >> 2))*K + (c0 & 3)*8;

  for (int kk = 0; kk < K; kk += 32) {
    gld16(&sA[c0*8], A + aOff0 + kk);
    gld16(&sA[c1*8], A + aOff1 + kk);
    gld16(&sB[c0*8], W + bOff0 + kk);
    __syncthreads();
    bf16x8 af[4], bfr[2];
#pragma unroll
    for (int i = 0; i < 4; i++)
      af[i] = *(const bf16x8*)&sA[(wm*64 + i*16 + col)*32 + quad*8];
#pragma unroll
    for (int j = 0; j < 2; j++)
      bfr[j] = *(const bf16x8*)&sB[(wn*32 + j*16 + col)*32 + quad*8];
#pragma unroll
    for (int i = 0; i < 4; i++)
#pragma unroll
      for (int j = 0; j < 2; j++)
        acc[i][j] = __builtin_amdgcn_mfma_f32_16x16x32_bf16(af[i], bfr[j], acc[i][j], 0, 0, 0);
    __syncthreads();
  }

  const bool f32o = (outMode == 1) || (outMode == -1 && *flag != 0u);
#pragma unroll
  for (int i = 0; i < 4; i++)
#pragma unroll
    for (int j = 0; j < 2; j++)
#pragma unroll
      for (int r = 0; r < 4; r++) {
        int grow = bm*128 + wm*64 + i*16 + quad*4 + r;
        int gcol = bn*64 + wn*32 + j*16 + col;
        size_t idx = (size_t)grow*N + gcol;
        float v = acc[i][j][r];
        if (f32o) ((float*)C)[idx] = v;
        else      ((u16*)C)[idx]   = f2bf(v);
      }
}

// ---------------- Causal flash attention (r5 structure, verified 73-74us:
// QBLK=64, grid 32x32 heavy-first, K/V double-buffered, pre-swizzled sV,
// defer-max THR=8, lane-partial li). FROZEN.
__global__ __launch_bounds__(256) void attn(
    const u16* __restrict__ Q, const u16* __restrict__ Kv,
    const u16* __restrict__ Vt, u16* __restrict__ O)
{
  __shared__ __align__(16) u16 sK[2][64*72];      // [buf][t][dh], stride 72
  __shared__ __align__(16) u16 sV[2][2][64*32];   // [buf][ts][slot], gld16-linear
  __shared__ __align__(16) u16 sP[4][16*72];      // per-wave P [q][t], stride 72

  const int tid  = threadIdx.x;
  const int lane = tid & 63;
  const int w    = tid >> 6;
  const int col = lane & 15, quad = lane >> 4;
  const int bh = blockIdx.x;
  const int qt = 31 - (int)blockIdx.y;            // heavy-first dispatch order
  const int b = bh >> 4, h = bh & 15;
  const size_t base  = (size_t)b*Ss*Dd + (size_t)h*64;
  const size_t vbase = (size_t)bh*64*Ss;

  const int krow = tid >> 2;              // K stage: row 0..63
  const int kch  = (tid & 3) * 2;         // 16B-chunk col {0,2,4,6}
  const int vrow = tid >> 2;
  const int vcp  = (tid & 3) ^ (vrow & 3) ^ ((vrow >> 2) & 3);
  const u16* Vh = Vt + vbase + (size_t)vrow*Ss + vcp*8;
  const int xorv = quad ^ (col & 3) ^ ((col >> 2) & 3);  // PV read swizzle
  u16* sPw = &sP[w][0];
  const float L2E = 1.44269504f;

  const int q0 = qt * 64;
  const int nk = qt + 1;                  // 64-t tiles
  const int qmin = q0 + w*16;

  bf16x8 qf0, qf1;
  {
    const size_t qoff = base + (size_t)(q0 + w*16 + col)*Dd + quad*8;
    qf0 = *(const bf16x8*)(Q + qoff);
    qf1 = *(const bf16x8*)(Q + qoff + 32);
  }
  floatx4 oacc[4] = {};
  float mi[4], li[4];
#pragma unroll
  for (int r = 0; r < 4; r++) { mi[r] = -1e30f; li[r] = 0.0f; }

  // -------- prologue: stage tile 0 into buffer 0
  {
    const u16* kg = Kv + base + (size_t)krow*Dd + kch*8;
    bf16x8 ka = *(const bf16x8*)kg;
    bf16x8 kb = *(const bf16x8*)(kg + 8);
    gld16(&sV[0][0][tid*8], Vh);
    gld16(&sV[0][1][tid*8], Vh + 32);
    *(bf16x8*)&sK[0][krow*72 + kch*8]     = ka;
    *(bf16x8*)&sK[0][krow*72 + kch*8 + 8] = kb;
    __syncthreads();                      // drains gld16 + ds_writes
  }

  for (int kt = 0; kt < nk; kt++) {
    const int t0 = kt*64;
    const int cur = kt & 1, nxt = cur ^ 1;
    const bool more = (kt + 1 < nk);
    bf16x8 ka, kb;
    if (more) {                           // issue next-tile loads early
      const u16* kg = Kv + base + (size_t)(t0 + 64 + krow)*Dd + kch*8;
      ka = *(const bf16x8*)kg;
      kb = *(const bf16x8*)(kg + 8);
      gld16(&sV[nxt][0][tid*8], Vh + t0 + 64);
      gld16(&sV[nxt][1][tid*8], Vh + t0 + 96);
    }

    // ---- QK^T (4 t-subtiles x 2 k-halves); Q pre-scaled -> sc is the score
    floatx4 sc[4] = {};
    __builtin_amdgcn_s_setprio(1);
#pragma unroll
    for (int ts = 0; ts < 4; ts++) {
      bf16x8 k0 = *(const bf16x8*)&sK[cur][(ts*16 + col)*72 + quad*8];
      bf16x8 k1 = *(const bf16x8*)&sK[cur][(ts*16 + col)*72 + 32 + quad*8];
      sc[ts] = __builtin_amdgcn_mfma_f32_16x16x32_bf16(qf0, k0, sc[ts], 0,0,0);
      sc[ts] = __builtin_amdgcn_mfma_f32_16x16x32_bf16(qf1, k1, sc[ts], 0,0,0);
    }
    __builtin_amdgcn_s_setprio(0);

    // ---- mask (boundary tile only) + row max
    const bool boundary = (t0 + 63 > qmin);
    float mxr[4];
    float needmax = 0.0f;
#pragma unroll
    for (int r = 0; r < 4; r++) {
      if (boundary) {
        const int qr = q0 + w*16 + quad*4 + r;
        if (t0 +      col > qr) sc[0][r] = -1e30f;
        if (t0 + 16 + col > qr) sc[1][r] = -1e30f;
        if (t0 + 32 + col > qr) sc[2][r] = -1e30f;
        if (t0 + 48 + col > qr) sc[3][r] = -1e30f;
      }
      float mx = fmaxf(fmaxf(sc[0][r], sc[1][r]), fmaxf(sc[2][r], sc[3][r]));
      mx = fmaxf(mx, __shfl_xor(mx, 1, 64));
      mx = fmaxf(mx, __shfl_xor(mx, 2, 64));
      mx = fmaxf(mx, __shfl_xor(mx, 4, 64));
      mx = fmaxf(mx, __shfl_xor(mx, 8, 64));
      mxr[r] = mx;
      needmax = fmaxf(needmax, mx - mi[r]);
    }
    // ---- defer-max: only rescale when the running max grows past THR=8
    if (!__all(needmax <= 8.0f)) {
      float alr[4];
#pragma unroll
      for (int r = 0; r < 4; r++) {
        float mn = fmaxf(mi[r], mxr[r]);
        float al = exp2f((mi[r] - mn)*L2E);
        mi[r] = mn; li[r] *= al; alr[r] = al;
      }
#pragma unroll
      for (int db = 0; db < 4; db++)
#pragma unroll
        for (int r = 0; r < 4; r++) oacc[db][r] *= alr[r];
    }
    // ---- P = exp2((s - mi)*L2E), pack bf16 (HW cvt_pk), lane-partial li
#pragma unroll
    for (int r = 0; r < 4; r++) {
      const float nb = -mi[r]*L2E;
      float p0 = exp2f(fmaf(sc[0][r], L2E, nb));
      float p1 = exp2f(fmaf(sc[1][r], L2E, nb));
      float p2 = exp2f(fmaf(sc[2][r], L2E, nb));
      float p3 = exp2f(fmaf(sc[3][r], L2E, nb));
      unsigned int pk01 = cvtpk(p0, p1);
      unsigned int pk23 = cvtpk(p2, p3);
      const int rw = (quad*4 + r)*72;
      sPw[rw + col]      = (u16)pk01;
      sPw[rw + 16 + col] = (u16)(pk01 >> 16);
      sPw[rw + 32 + col] = (u16)pk23;
      sPw[rw + 48 + col] = (u16)(pk23 >> 16);
      // li from ROUNDED p (matches bf16 PV numerator); reduce deferred.
      li[r] += (u2f(pk01 << 16) + u2f(pk01 & 0xffff0000u))
             + (u2f(pk23 << 16) + u2f(pk23 & 0xffff0000u));
    }
    // ---- PV (same-wave LDS write->read: DS pipe in-order per wave)
    bf16x8 pa0 = *(const bf16x8*)&sPw[col*72 + quad*8];
    bf16x8 pa1 = *(const bf16x8*)&sPw[col*72 + 32 + quad*8];
    __builtin_amdgcn_s_setprio(1);
#pragma unroll
    for (int db = 0; db < 4; db++) {
      const int vs = (db*16 + col)*32 + xorv*8;
      bf16x8 vb0 = *(const bf16x8*)&sV[cur][0][vs];
      bf16x8 vb1 = *(const bf16x8*)&sV[cur][1][vs];
      oacc[db] = __builtin_amdgcn_mfma_f32_16x16x32_bf16(pa0, vb0, oacc[db], 0,0,0);
      oacc[db] = __builtin_amdgcn_mfma_f32_16x16x32_bf16(pa1, vb1, oacc[db], 0,0,0);
    }
    __builtin_amdgcn_s_setprio(0);

    if (more) {                           // write next K tile (compiler waits loads)
      *(bf16x8*)&sK[nxt][krow*72 + kch*8]     = ka;
      *(bf16x8*)&sK[nxt][krow*72 + kch*8 + 8] = kb;
    }
    __syncthreads();                      // drains gld16 + ds_writes; flips buffers
  }

  // -------- epilogue: reduce lane-partial li across the 16-lane row group
  float inv[4];
#pragma unroll
  for (int r = 0; r < 4; r++) {
    float s = li[r];
    s += __shfl_xor(s, 1, 64);
    s += __shfl_xor(s, 2, 64);
    s += __shfl_xor(s, 4, 64);
    s += __shfl_xor(s, 8, 64);
    inv[r] = 1.0f / s;
  }
#pragma unroll
  for (int db = 0; db < 4; db++)
#pragma unroll
    for (int r = 0; r < 4; r++)
      O[base + (size_t)(q0 + w*16 + quad*4 + r)*Dd + db*16 + col] =
          f2bf(oacc[db][r] * inv[r]);
}

extern "C" void kernel_launch(void* const* d_in, const int* in_sizes, int n_in,
                              void* d_out, int out_size, void* d_ws, size_t ws_size,
                              hipStream_t stream) {
  const void* x  = d_in[0];
  const void* wq = d_in[1];
  const void* wk = d_in[2];
  const void* wv = d_in[3];
  const void* wo = d_in[4];
  // d_in[5] = mask: causal tril, hardcoded in attn kernel.

  const size_t T  = Tt;
  const size_t WN = WNn;

  char* ws = (char*)d_ws;
  unsigned int* flag = (unsigned int*)ws;
  u16* xb  = (u16*)(ws + 256);
  u16* wqb = xb  + T;
  u16* wkb = wqb + WN;
  u16* wvb = wkb + WN;
  u16* wob = wvb + WN;
  u16* Qb  = wob + WN;
  u16* Kb  = Qb + T;
  u16* Vb  = Kb + T;                    // holds V^T per head: [b][h][64][S]
  u16* AO  = Vb + T;
  float2* tab = (float2*)(AO + T);      // RoPE table 2048x16 float2 = 256KB
                                        // total ws use ~48.5 MB

  // Resolve input dtype on the HOST from byte sizes (f32 = 16MB, bf16 = 8MB).
  int smode = -1;
  if (in_sizes && n_in > 0) {
    if (in_sizes[0] == (int)(T*4))      smode = 1;
    else if (in_sizes[0] == (int)(T*2)) smode = 0;
  }
  if (smode < 0)
    sniff<<<1, 1024, 0, stream>>>((const unsigned int*)x, flag, 65536);

  convert_all<<<4128, 256, 0, stream>>>(x, wq, wk, wv, wo, xb, smode, flag, tab);

  // QKV projection with fused RMSNorm+RoPE (table) / V-transpose epilogues,
  // both staged through LDS for coalesced writeback.
  gemm_bt<<<dim3(8, 32, 3), 256, 0, stream>>>(xb, wqb, wkb, wvb, Qb, Kb, Vb,
                                              4096, 1024, 1024, tab);
  attn<<<dim3(32, 32), 256, 0, stream>>>(Qb, Kb, Vb, AO);
  // Output projection: 128x64 tiles, 512 blocks = 2/CU.
  gemm_o<<<dim3(16, 32), 256, 0, stream>>>(AO, wob, d_out,
                                           4096, 1024, 1024, flag, smode);
}

// Round 11
// 233.192 us; speedup vs baseline: 1.1073x; 1.1073x over previous
//
#include <hip/hip_runtime.h>
#include <hip/hip_bf16.h>

#define Bb 2
#define Ss 2048
#define Dd 1024
#define Hh 16
#define Tt ((size_t)Bb*Ss*Dd)   // 4,194,304
#define WNn ((size_t)Dd*Dd)     // 1,048,576

typedef short bf16x8 __attribute__((ext_vector_type(8)));
typedef short bf16x4 __attribute__((ext_vector_type(4)));
typedef float floatx4 __attribute__((ext_vector_type(4)));
typedef unsigned short u16;

__device__ inline void gld16(void* lds, const void* g) {
  __builtin_amdgcn_global_load_lds(
      (const __attribute__((address_space(1))) unsigned int*)g,
      (__attribute__((address_space(3))) unsigned int*)lds, 16, 0, 0);
}

__device__ inline float bf2f(u16 u) {
  unsigned int x = ((unsigned int)u) << 16;
  float f; __builtin_memcpy(&f, &x, 4); return f;
}
__device__ inline u16 f2bf(float f) {
  unsigned int x; __builtin_memcpy(&x, &f, 4);
  x = (x + 0x7fff + ((x >> 16) & 1)) >> 16;   // RNE
  return (u16)x;
}
__device__ inline float u2f(unsigned int x) {
  float f; __builtin_memcpy(&f, &x, 4); return f;
}
// HW packed f32->bf16 (RNE), no builtin on gfx950 -> inline asm.
__device__ inline unsigned int cvtpk(float lo, float hi) {
  unsigned int r;
  asm("v_cvt_pk_bf16_f32 %0, %1, %2" : "=v"(r) : "v"(lo), "v"(hi));
  return r;
}

// ---------------- dtype sniffer (FALLBACK ONLY; host normally resolves dtype
// from in_sizes).
__global__ void sniff(const unsigned int* __restrict__ x, unsigned int* __restrict__ flag,
                      int nwords) {
  __shared__ int cnt;
  if (threadIdx.x == 0) cnt = 0;
  __syncthreads();
  int local = 0;
  for (int i = threadIdx.x; i < nwords; i += blockDim.x) {
    unsigned int wd = x[i];
    if (((wd >> 7)  & 0xFFu) == 0xFFu) local++;
    if (((wd >> 23) & 0xFFu) == 0xFFu) local++;
  }
  atomicAdd(&cnt, local);
  __syncthreads();
  if (threadIdx.x == 0) *flag = (cnt >= 64) ? 1u : 0u;
}

// ---------------- normalize ALL input tensors to bf16 in one launch, and
// (last 32 blocks) precompute the RoPE cos/sin table tab[s][f], f<16.
__global__ __launch_bounds__(256) void convert_all(
    const void* __restrict__ x,  const void* __restrict__ wq,
    const void* __restrict__ wk, const void* __restrict__ wv,
    const void* __restrict__ wo, u16* __restrict__ dst,
    int smode, const unsigned int* __restrict__ flag,
    float2* __restrict__ tab) {
  const int gb = blockIdx.x;
  if (gb >= 4096) {                       // RoPE table: 32 blocks x 256 x 4
    int e = (gb - 4096)*1024 + threadIdx.x*4;
#pragma unroll
    for (int j = 0; j < 4; j++, e++) {
      int s = e >> 4, f = e & 15;
      float freq = exp2f((-10.0f/15.0f) * (float)f);
      float th = (float)s * freq;
      float sn, c;
      sincosf(th, &sn, &c);
      tab[e] = make_float2(c, sn);
    }
    return;
  }
  const void* src; size_t base; int lb;
  if (gb < 2048)      { src = x;  base = 0;            lb = gb;        }
  else if (gb < 2560) { src = wq; base = Tt;           lb = gb - 2048; }
  else if (gb < 3072) { src = wk; base = Tt + WNn;     lb = gb - 2560; }
  else if (gb < 3584) { src = wv; base = Tt + 2*WNn;   lb = gb - 3072; }
  else                { src = wo; base = Tt + 3*WNn;   lb = gb - 3584; }
  const size_t off = (size_t)lb*2048 + threadIdx.x*8;
  const bool f32 = (smode >= 0) ? (smode == 1) : (*flag != 0u);
  bf16x8 v;
  if (f32) {
    const float* s = (const float*)src + off;
#pragma unroll
    for (int j = 0; j < 8; j++) v[j] = (short)f2bf(s[j]);
  } else {
    v = *(const bf16x8*)((const u16*)src + off);
  }
  *(bf16x8*)(dst + base + off) = v;
}

// ---------------- QKV GEMM: C = A(MxK) * W^T, W stored (N,K) row-major.
// m97 structure: 128x128 tile, BK=32, global_load_lds width=16.
// r8-proven DIRECT epilogues (the r9 LDS-staged variant regressed):
// z 0/1 (Q,K): fused RMSNorm+RoPE(table); z=2: V transposed per head.
__global__ __launch_bounds__(256) void gemm_bt(
    const u16* __restrict__ A,
    const u16* __restrict__ W0, const u16* __restrict__ W1, const u16* __restrict__ W2,
    void* __restrict__ C0, void* __restrict__ C1, void* __restrict__ C2,
    int M, int N, int K, const float2* __restrict__ tab)
{
  const u16* W; void* C;
  if (blockIdx.z == 0)      { W = W0; C = C0; }
  else if (blockIdx.z == 1) { W = W1; C = C1; }
  else                      { W = W2; C = C2; }

  __shared__ __align__(16) u16 sA[128*32];
  __shared__ __align__(16) u16 sB[128*32];

  const int tid  = threadIdx.x;
  const int lane = tid & 63;
  const int w    = tid >> 6;
  const int wm = w >> 1, wn = w & 1;
  const int col = lane & 15, quad = lane >> 4;
  const int bm = blockIdx.y, bn = blockIdx.x;

  floatx4 acc[4][4] = {};

  const int c0 = tid, c1 = tid + 256;
  const size_t aOff0 = (size_t)(bm*128 + (c0 >> 2))*K + (c0 & 3)*8;
  const size_t aOff1 = (size_t)(bm*128 + (c1 >> 2))*K + (c1 & 3)*8;
  const size_t bOff0 = (size_t)(bn*128 + (c0 >> 2))*K + (c0 & 3)*8;
  const size_t bOff1 = (size_t)(bn*128 + (c1 >> 2))*K + (c1 & 3)*8;

  for (int kk = 0; kk < K; kk += 32) {
    gld16(&sA[c0*8], A + aOff0 + kk);
    gld16(&sA[c1*8], A + aOff1 + kk);
    gld16(&sB[c0*8], W + bOff0 + kk);
    gld16(&sB[c1*8], W + bOff1 + kk);
    __syncthreads();
    bf16x8 af[4], bfr[4];
#pragma unroll
    for (int i = 0; i < 4; i++)
      af[i] = *(const bf16x8*)&sA[(wm*64 + i*16 + col)*32 + quad*8];
#pragma unroll
    for (int j = 0; j < 4; j++)
      bfr[j] = *(const bf16x8*)&sB[(wn*64 + j*16 + col)*32 + quad*8];
#pragma unroll
    for (int i = 0; i < 4; i++)
#pragma unroll
      for (int j = 0; j < 4; j++)
        acc[i][j] = __builtin_amdgcn_mfma_f32_16x16x32_bf16(af[i], bfr[j], acc[i][j], 0, 0, 0);
    __syncthreads();
  }

  if (blockIdx.z == 2) {
    // V: transposed epilogue -> Vt[b][h][dl][s], bf16x4 along s.
    u16* Ct = (u16*)C;
#pragma unroll
    for (int i = 0; i < 4; i++)
#pragma unroll
      for (int j = 0; j < 4; j++) {
        int d = bn*128 + wn*64 + j*16 + col;
        int g = bm*128 + wm*64 + i*16 + quad*4;
        int hh = d >> 6, dl = d & 63;
        int bb = g >> 11, s = g & (Ss - 1);
        bf16x4 pk;
#pragma unroll
        for (int r = 0; r < 4; r++) pk[r] = (short)f2bf(acc[i][j][r]);
        *(bf16x4*)&Ct[((size_t)(bb*Hh + hh)*64 + dl)*Ss + s] = pk;
      }
  } else {
    // Q/K: fused RMSNorm (head = wave's 64 cols) + RoPE from table; Q also
    // pre-scaled by 1/sqrt(DH)=0.125 (pow2, exact in bf16).
    const float qs = (blockIdx.z == 0) ? 0.125f : 1.0f;
    u16* Co = (u16*)C;
    const size_t cb = (size_t)(bn*128 + wn*64 + col);
#pragma unroll
    for (int i = 0; i < 4; i++)
#pragma unroll
      for (int r = 0; r < 4; r++) {
        float ss = 0.0f;
#pragma unroll
        for (int j = 0; j < 4; j++) ss += acc[i][j][r]*acc[i][j][r];
        ss += __shfl_xor(ss, 1, 64);
        ss += __shfl_xor(ss, 2, 64);
        ss += __shfl_xor(ss, 4, 64);
        ss += __shfl_xor(ss, 8, 64);
        float rn = rsqrtf(ss*(1.0f/64.0f) + 1e-6f) * qs;
        int grow = bm*128 + wm*64 + i*16 + quad*4 + r;
        float2 cs = tab[(grow & (Ss - 1))*16 + col];
        float c = cs.x, sn = cs.y;
        float x0 = acc[i][0][r]*rn, x1 = acc[i][1][r]*rn;
        float x2 = acc[i][2][r]*rn, x3 = acc[i][3][r]*rn;
        size_t rowb = (size_t)grow*N + cb;
        Co[rowb]      = f2bf(x0*c + x2*sn);
        Co[rowb + 16] = f2bf(x1);
        Co[rowb + 32] = f2bf(x2*c - x0*sn);
        Co[rowb + 48] = f2bf(x3);
      }
  }
}

// ---------------- O-projection GEMM: 128x64 tile -> 512 blocks = 2/CU
// (128x128 was 256 blocks = 1/CU: barriers fully exposed).
__global__ __launch_bounds__(256) void gemm_o(
    const u16* __restrict__ A, const u16* __restrict__ W, void* __restrict__ C,
    int M, int N, int K, const unsigned int* __restrict__ flag, int outMode)
{
  __shared__ __align__(16) u16 sA[128*32];
  __shared__ __align__(16) u16 sB[64*32];

  const int tid  = threadIdx.x;
  const int lane = tid & 63;
  const int w    = tid >> 6;
  const int wm = w >> 1, wn = w & 1;
  const int col = lane & 15, quad = lane >> 4;
  const int bm = blockIdx.y, bn = blockIdx.x;

  floatx4 acc[4][2] = {};

  const int c0 = tid, c1 = tid + 256;
  const size_t aOff0 = (size_t)(bm*128 + (c0 >> 2))*K + (c0 & 3)*8;
  const size_t aOff1 = (size_t)(bm*128 + (c1 >> 2))*K + (c1 & 3)*8;
  const size_t bOff0 = (size_t)(bn*64  + (c0 >> 2))*K + (c0 & 3)*8;

  for (int kk = 0; kk < K; kk += 32) {
    gld16(&sA[c0*8], A + aOff0 + kk);
    gld16(&sA[c1*8], A + aOff1 + kk);
    gld16(&sB[c0*8], W + bOff0 + kk);
    __syncthreads();
    bf16x8 af[4], bfr[2];
#pragma unroll
    for (int i = 0; i < 4; i++)
      af[i] = *(const bf16x8*)&sA[(wm*64 + i*16 + col)*32 + quad*8];
#pragma unroll
    for (int j = 0; j < 2; j++)
      bfr[j] = *(const bf16x8*)&sB[(wn*32 + j*16 + col)*32 + quad*8];
#pragma unroll
    for (int i = 0; i < 4; i++)
#pragma unroll
      for (int j = 0; j < 2; j++)
        acc[i][j] = __builtin_amdgcn_mfma_f32_16x16x32_bf16(af[i], bfr[j], acc[i][j], 0, 0, 0);
    __syncthreads();
  }

  const bool f32o = (outMode == 1) || (outMode == -1 && *flag != 0u);
#pragma unroll
  for (int i = 0; i < 4; i++)
#pragma unroll
    for (int j = 0; j < 2; j++)
#pragma unroll
      for (int r = 0; r < 4; r++) {
        int grow = bm*128 + wm*64 + i*16 + quad*4 + r;
        int gcol = bn*64 + wn*32 + j*16 + col;
        size_t idx = (size_t)grow*N + gcol;
        float v = acc[i][j][r];
        if (f32o) ((float*)C)[idx] = v;
        else      ((u16*)C)[idx]   = f2bf(v);
      }
}

// ---------------- Causal flash attention, SWAPPED QK^T.
// r5 skeleton (QBLK=64, grid 32x32 heavy-first, K/V dbuf, pre-swizzled sV,
// defer-max THR=8) but QK^T computes mfma(K, Q): operand LDS reads are
// IDENTICAL (A/B frags both read [lane&15][quad*8+j]); the score layout
// transposes to sc[ts][r] = S[t=t0+ts*16+quad*4+r][q = q0+w*16+col], so each
// lane owns one q-row: row-max = 15 in-lane fmax + 2 shfl (was 16 shfl),
// mi/li are scalars, P-store = 4 ds_write_b64 (was 16 scattered b16).
// sP content layout [q][t] is unchanged -> PV + output epilogue identical.
// Per-q factors (alpha on the rare rescale, 1/li at epilogue) bounce through
// tiny per-wave LDS (same-wave DS in-order, no barrier).
__global__ __launch_bounds__(256) void attn(
    const u16* __restrict__ Q, const u16* __restrict__ Kv,
    const u16* __restrict__ Vt, u16* __restrict__ O)
{
  __shared__ __align__(16) u16 sK[2][64*72];      // [buf][t][dh], stride 72
  __shared__ __align__(16) u16 sV[2][2][64*32];   // [buf][ts][slot], gld16-linear
  __shared__ __align__(16) u16 sP[4][16*72];      // per-wave P [q][t], stride 72
  __shared__ float sAl[4][16];                    // per-wave alpha bounce
  __shared__ float sLi[4][16];                    // per-wave 1/li bounce

  const int tid  = threadIdx.x;
  const int lane = tid & 63;
  const int w    = tid >> 6;
  const int col = lane & 15, quad = lane >> 4;
  const int bh = blockIdx.x;
  const int qt = 31 - (int)blockIdx.y;            // heavy-first dispatch order
  const int b = bh >> 4, h = bh & 15;
  const size_t base  = (size_t)b*Ss*Dd + (size_t)h*64;
  const size_t vbase = (size_t)bh*64*Ss;

  const int krow = tid >> 2;              // K stage: row 0..63
  const int kch  = (tid & 3) * 2;         // 16B-chunk col {0,2,4,6}
  const int vrow = tid >> 2;
  const int vcp  = (tid & 3) ^ (vrow & 3) ^ ((vrow >> 2) & 3);
  const u16* Vh = Vt + vbase + (size_t)vrow*Ss + vcp*8;
  const int xorv = quad ^ (col & 3) ^ ((col >> 2) & 3);  // PV read swizzle
  u16* sPw = &sP[w][0];
  const float L2E = 1.44269504f;

  const int q0 = qt * 64;
  const int nk = qt + 1;                  // 64-t tiles
  const int qg = q0 + w*16 + col;         // this lane's softmax row (swapped)

  bf16x8 qf0, qf1;
  {
    const size_t qoff = base + (size_t)(q0 + w*16 + col)*Dd + quad*8;
    qf0 = *(const bf16x8*)(Q + qoff);
    qf1 = *(const bf16x8*)(Q + qoff + 32);
  }
  floatx4 oacc[4] = {};                   // O[q=q0+w*16+quad*4+r][d=db*16+col]
  float mi = -1e30f, li = 0.0f;           // per-lane scalars (row qg)

  // -------- prologue: stage tile 0 into buffer 0
  {
    const u16* kg = Kv + base + (size_t)krow*Dd + kch*8;
    bf16x8 ka = *(const bf16x8*)kg;
    bf16x8 kb = *(const bf16x8*)(kg + 8);
    gld16(&sV[0][0][tid*8], Vh);
    gld16(&sV[0][1][tid*8], Vh + 32);
    *(bf16x8*)&sK[0][krow*72 + kch*8]     = ka;
    *(bf16x8*)&sK[0][krow*72 + kch*8 + 8] = kb;
    __syncthreads();                      // drains gld16 + ds_writes
  }

  for (int kt = 0; kt < nk; kt++) {
    const int t0 = kt*64;
    const int cur = kt & 1, nxt = cur ^ 1;
    const bool more = (kt + 1 < nk);
    bf16x8 ka, kb;
    if (more) {                           // issue next-tile loads early
      const u16* kg = Kv + base + (size_t)(t0 + 64 + krow)*Dd + kch*8;
      ka = *(const bf16x8*)kg;
      kb = *(const bf16x8*)(kg + 8);
      gld16(&sV[nxt][0][tid*8], Vh + t0 + 64);
      gld16(&sV[nxt][1][tid*8], Vh + t0 + 96);
    }

    // ---- QK^T swapped: sc[ts][r] = S[t=t0+ts*16+quad*4+r][q=qg]
    floatx4 sc[4] = {};
    __builtin_amdgcn_s_setprio(1);
#pragma unroll
    for (int ts = 0; ts < 4; ts++) {
      bf16x8 k0 = *(const bf16x8*)&sK[cur][(ts*16 + col)*72 + quad*8];
      bf16x8 k1 = *(const bf16x8*)&sK[cur][(ts*16 + col)*72 + 32 + quad*8];
      sc[ts] = __builtin_amdgcn_mfma_f32_16x16x32_bf16(k0, qf0, sc[ts], 0,0,0);
      sc[ts] = __builtin_amdgcn_mfma_f32_16x16x32_bf16(k1, qf1, sc[ts], 0,0,0);
    }
    __builtin_amdgcn_s_setprio(0);

    // ---- mask (boundary tile only): t > qg
    const bool boundary = (t0 + 63 > q0 + w*16);
    if (boundary) {
      const int tb = t0 + quad*4 - qg;    // mask iff tb + ts*16 + r > 0
#pragma unroll
      for (int ts = 0; ts < 4; ts++)
#pragma unroll
        for (int r = 0; r < 4; r++)
          if (tb + ts*16 + r > 0) sc[ts][r] = -1e30f;
    }
    // ---- row max: 15 in-lane fmax + 2 cross-quad shuffles
    float mx = fmaxf(fmaxf(sc[0][0], sc[0][1]), fmaxf(sc[0][2], sc[0][3]));
#pragma unroll
    for (int ts = 1; ts < 4; ts++)
      mx = fmaxf(mx, fmaxf(fmaxf(sc[ts][0], sc[ts][1]),
                           fmaxf(sc[ts][2], sc[ts][3])));
    mx = fmaxf(mx, __shfl_xor(mx, 16, 64));
    mx = fmaxf(mx, __shfl_xor(mx, 32, 64));   // all 4 quads of a row agree
    // ---- defer-max: rescale only when the running max grows past THR=8
    if (!__all(mx - mi <= 8.0f)) {
      float mn = fmaxf(mi, mx);
      float al = exp2f((mi - mn)*L2E);
      mi = mn; li *= al;
      if (quad == 0) sAl[w][col] = al;    // one writer per row
      // same-wave DS in-order: fetch per-output-row factors
      float a0 = sAl[w][quad*4 + 0], a1 = sAl[w][quad*4 + 1];
      float a2 = sAl[w][quad*4 + 2], a3 = sAl[w][quad*4 + 3];
#pragma unroll
      for (int db = 0; db < 4; db++) {
        oacc[db][0] *= a0; oacc[db][1] *= a1;
        oacc[db][2] *= a2; oacc[db][3] *= a3;
      }
    }
    // ---- P = exp2((s-mi)*L2E); 4 consecutive t -> one ds_write_b64 per ts
    const float nb = -mi*L2E;
#pragma unroll
    for (int ts = 0; ts < 4; ts++) {
      float p0 = exp2f(fmaf(sc[ts][0], L2E, nb));
      float p1 = exp2f(fmaf(sc[ts][1], L2E, nb));
      float p2 = exp2f(fmaf(sc[ts][2], L2E, nb));
      float p3 = exp2f(fmaf(sc[ts][3], L2E, nb));
      unsigned int pk01 = cvtpk(p0, p1);
      unsigned int pk23 = cvtpk(p2, p3);
      *(uint2*)&sPw[col*72 + ts*16 + quad*4] = make_uint2(pk01, pk23);
      // li from ROUNDED p (matches bf16 PV numerator); lane-partial.
      li += (u2f(pk01 << 16) + u2f(pk01 & 0xffff0000u))
          + (u2f(pk23 << 16) + u2f(pk23 & 0xffff0000u));
    }
    // ---- PV (unchanged; same-wave LDS write->read, DS in-order per wave)
    bf16x8 pa0 = *(const bf16x8*)&sPw[col*72 + quad*8];
    bf16x8 pa1 = *(const bf16x8*)&sPw[col*72 + 32 + quad*8];
    __builtin_amdgcn_s_setprio(1);
#pragma unroll
    for (int db = 0; db < 4; db++) {
      const int vs = (db*16 + col)*32 + xorv*8;
      bf16x8 vb0 = *(const bf16x8*)&sV[cur][0][vs];
      bf16x8 vb1 = *(const bf16x8*)&sV[cur][1][vs];
      oacc[db] = __builtin_amdgcn_mfma_f32_16x16x32_bf16(pa0, vb0, oacc[db], 0,0,0);
      oacc[db] = __builtin_amdgcn_mfma_f32_16x16x32_bf16(pa1, vb1, oacc[db], 0,0,0);
    }
    __builtin_amdgcn_s_setprio(0);

    if (more) {                           // write next K tile (compiler waits loads)
      *(bf16x8*)&sK[nxt][krow*72 + kch*8]     = ka;
      *(bf16x8*)&sK[nxt][krow*72 + kch*8 + 8] = kb;
    }
    __syncthreads();                      // drains gld16 + ds_writes; flips buffers
  }

  // -------- epilogue: complete li across the quad axis, bounce 1/li per row
  li += __shfl_xor(li, 16, 64);
  li += __shfl_xor(li, 32, 64);
  if (quad == 0) sLi[w][col] = 1.0f / li;
  float i0 = sLi[w][quad*4 + 0], i1 = sLi[w][quad*4 + 1];
  float i2 = sLi[w][quad*4 + 2], i3 = sLi[w][quad*4 + 3];
#pragma unroll
  for (int db = 0; db < 4; db++) {
    const size_t rb = base + (size_t)(q0 + w*16 + quad*4)*Dd + db*16 + col;
    O[rb]        = f2bf(oacc[db][0] * i0);
    O[rb + Dd]   = f2bf(oacc[db][1] * i1);
    O[rb + 2*Dd] = f2bf(oacc[db][2] * i2);
    O[rb + 3*Dd] = f2bf(oacc[db][3] * i3);
  }
}

extern "C" void kernel_launch(void* const* d_in, const int* in_sizes, int n_in,
                              void* d_out, int out_size, void* d_ws, size_t ws_size,
                              hipStream_t stream) {
  const void* x  = d_in[0];
  const void* wq = d_in[1];
  const void* wk = d_in[2];
  const void* wv = d_in[3];
  const void* wo = d_in[4];
  // d_in[5] = mask: causal tril, hardcoded in attn kernel.

  const size_t T  = Tt;
  const size_t WN = WNn;

  char* ws = (char*)d_ws;
  unsigned int* flag = (unsigned int*)ws;
  u16* xb  = (u16*)(ws + 256);
  u16* wqb = xb  + T;
  u16* wkb = wqb + WN;
  u16* wvb = wkb + WN;
  u16* wob = wvb + WN;
  u16* Qb  = wob + WN;
  u16* Kb  = Qb + T;
  u16* Vb  = Kb + T;                    // holds V^T per head: [b][h][64][S]
  u16* AO  = Vb + T;
  float2* tab = (float2*)(AO + T);      // RoPE table 2048x16 float2 = 256KB
                                        // total ws use ~48.5 MB

  // Resolve input dtype on the HOST from byte sizes (f32 = 16MB, bf16 = 8MB).
  int smode = -1;
  if (in_sizes && n_in > 0) {
    if (in_sizes[0] == (int)(T*4))      smode = 1;
    else if (in_sizes[0] == (int)(T*2)) smode = 0;
  }
  if (smode < 0)
    sniff<<<1, 1024, 0, stream>>>((const unsigned int*)x, flag, 65536);

  convert_all<<<4128, 256, 0, stream>>>(x, wq, wk, wv, wo, xb, smode, flag, tab);

  // QKV projection with fused RMSNorm+RoPE (table) / V-transpose epilogues.
  gemm_bt<<<dim3(8, 32, 3), 256, 0, stream>>>(xb, wqb, wkb, wvb, Qb, Kb, Vb,
                                              4096, 1024, 1024, tab);
  attn<<<dim3(32, 32), 256, 0, stream>>>(Qb, Kb, Vb, AO);
  // Output projection: 128x64 tiles, 512 blocks = 2/CU.
  gemm_o<<<dim3(16, 32), 256, 0, stream>>>(AO, wob, d_out,
                                           4096, 1024, 1024, flag, smode);
}